// Round 4
// baseline (56.165 us; speedup 1.0000x reference)
//
#include <hip/hip_runtime.h>
#include <math.h>

#define NB   32
#define CIN  4
#define COUT 64
#define TT   6
#define VV   512
#define P_OFF (NB*COUT*TT*VV)   // out then p in d_out
#define SPLITS 8
#define CH   (VV/SPLITS)        // 64 rows per chunk
#define NROW 24                 // c*6+t rows of x per batch
#define E_FLOATS (2*NB*VV)      // e_i + e_j in ws

// ---------------------------------------------------------------------------
// Kernel 1: e_i[n,v], e_j[n,v]  (collapsed xc -> x1 -> e chain)
// ---------------------------------------------------------------------------
__global__ __launch_bounds__(256) void e_kernel(
    const float* __restrict__ x,
    const float* __restrict__ conv_w,
    const float* __restrict__ conv_b,
    const float* __restrict__ l2_w,
    const float* __restrict__ l2_b,
    const float* __restrict__ l1_w,
    float* __restrict__ e)
{
    __shared__ float W1[CIN], W2[CIN], cst[2];
    int tid = threadIdx.x;
    if (tid < CIN) {
        float w1 = 0.f, w2 = 0.f;
        for (int o = 0; o < COUT; ++o) {
            w1 += l1_w[o]        * conv_w[o*CIN + tid];
            w2 += l1_w[COUT + o] * conv_w[o*CIN + tid];
        }
        W1[tid] = w1; W2[tid] = w2;
    }
    if (tid == CIN) {
        float B1 = 0.f, B2 = 0.f, S1 = 0.f, S2 = 0.f;
        for (int o = 0; o < COUT; ++o) {
            B1 += l1_w[o]        * conv_b[o];
            B2 += l1_w[COUT + o] * conv_b[o];
            S1 += l1_w[o];
            S2 += l1_w[COUT + o];
        }
        float Ls = 0.f;
        for (int t = 0; t < TT; ++t) Ls += l2_w[t];
        cst[0] = Ls*B1 + l2_b[0]*S1;
        cst[1] = Ls*B2 + l2_b[0]*S2;
    }
    __syncthreads();

    int idx = blockIdx.x * 256 + tid;      // n*V + v
    int n = idx >> 9, v = idx & (VV-1);
    float ei = cst[0], ej = cst[1];
    #pragma unroll
    for (int c = 0; c < CIN; ++c) {
        float wc1 = W1[c], wc2 = W2[c];
        #pragma unroll
        for (int t = 0; t < TT; ++t) {
            float xv = x[((n*CIN + c)*TT + t)*VV + v];
            float lw = l2_w[t];
            ei += lw*wc1*xv;
            ej += lw*wc2*xv;
        }
    }
    e[idx]         = ei;
    e[NB*VV + idx] = ej;
}

// ---------------------------------------------------------------------------
// Kernel 2 (fused): masked softmax rows -> p (global) AND in-register
// rank-1 accumulation of y_part[r][w] = sum_{v in chunk} x[n,r,v]*p[n,v,w].
// Wave q owns rows i == q (mod 4) of the 64-row chunk; lane owns w = k*64+lane
// for k=0..7; p stays in registers (acc[25][8] per lane).
// ---------------------------------------------------------------------------
__global__ __launch_bounds__(256, 1) void fused_kernel(
    const float* __restrict__ x,
    const int*   __restrict__ A,
    const float* __restrict__ e,
    const float* __restrict__ l1_b,
    float*       __restrict__ p,
    float*       __restrict__ ypart)
{
    __shared__ float xst[CH][NROW];      // 6 KB, xst[v_local][r]
    __shared__ float red2[VV*25];        // 51.2 KB, red2[w*25 + r]

    int s = blockIdx.x;                  // chunk
    int n = blockIdx.y;
    int tid = threadIdx.x;
    int lane = tid & 63;
    int q = tid >> 6;                    // wave id

    // stage x slab transposed: xst[v][r]
    for (int l = tid; l < NROW*CH; l += 256) {
        int r = l >> 6, v = l & 63;
        xst[v][r] = x[((size_t)n*NROW + r)*VV + s*CH + v];
    }

    float l1b_val = l1_b[0];
    float ejv[8];
    #pragma unroll
    for (int k = 0; k < 8; ++k)
        ejv[k] = e[NB*VV + n*VV + k*64 + lane];

    const int* mbase = A + (size_t)(n*8 + 7)*VV*VV;

    float acc[25][8];
    #pragma unroll
    for (int r = 0; r < 25; ++r)
        #pragma unroll
        for (int k = 0; k < 8; ++k) acc[r][k] = 0.f;

    __syncthreads();   // xst ready

    // prefetch first row's mask + bias
    int mnext[8];
    float bnext;
    {
        int i = s*CH + q;
        const int* mr = mbase + (size_t)i*VV + lane;
        #pragma unroll
        for (int k = 0; k < 8; ++k) mnext[k] = mr[k*64];
        bnext = e[n*VV + i];
    }

    for (int b = 0; b < 16; ++b) {
        int il = b*4 + q;
        int i  = s*CH + il;

        int mcur[8];
        #pragma unroll
        for (int k = 0; k < 8; ++k) mcur[k] = mnext[k];
        float bias = bnext + l1b_val;

        if (b < 15) {   // prefetch next row (hidden under FMA burst)
            const int* mr = mbase + (size_t)(i + 4)*VV + lane;
            #pragma unroll
            for (int k = 0; k < 8; ++k) mnext[k] = mr[k*64];
            bnext = e[n*VV + i + 4];
        }

        // softmax row i, j = k*64 + lane
        float sv[8];
        #pragma unroll
        for (int k = 0; k < 8; ++k) {
            float t = bias + ejv[k];
            t = (t >= 0.f) ? t : 0.2f * t;
            sv[k] = (mcur[k] == 0) ? -INFINITY : t;
        }
        float m = -INFINITY;
        #pragma unroll
        for (int k = 0; k < 8; ++k) m = fmaxf(m, sv[k]);
        #pragma unroll
        for (int off = 32; off; off >>= 1) m = fmaxf(m, __shfl_xor(m, off));

        float sum = 0.f;
        if (m > -INFINITY) {
            #pragma unroll
            for (int k = 0; k < 8; ++k) { sv[k] = __expf(sv[k] - m); sum += sv[k]; }
        } else {
            #pragma unroll
            for (int k = 0; k < 8; ++k) sv[k] = 0.f;
        }
        #pragma unroll
        for (int off = 32; off; off >>= 1) sum += __shfl_xor(sum, off);
        float inv = (sum > 0.f) ? 1.f / sum : 0.f;

        float pk[8];
        #pragma unroll
        for (int k = 0; k < 8; ++k) pk[k] = sv[k] * inv;

        // write p row (coalesced 256B per k)
        float* prow = p + (size_t)(n*VV + i)*VV + lane;
        #pragma unroll
        for (int k = 0; k < 8; ++k) prow[k*64] = pk[k];

        // rank-1 update from registers; x via broadcast LDS float4
        const float4* xr4 = (const float4*)&xst[il][0];
        #pragma unroll
        for (int r4 = 0; r4 < 6; ++r4) {
            float4 xv = xr4[r4];
            #pragma unroll
            for (int k = 0; k < 8; ++k) {
                acc[r4*4+0][k] = fmaf(xv.x, pk[k], acc[r4*4+0][k]);
                acc[r4*4+1][k] = fmaf(xv.y, pk[k], acc[r4*4+1][k]);
                acc[r4*4+2][k] = fmaf(xv.z, pk[k], acc[r4*4+2][k]);
                acc[r4*4+3][k] = fmaf(xv.w, pk[k], acc[r4*4+3][k]);
            }
        }
        #pragma unroll
        for (int k = 0; k < 8; ++k) acc[24][k] += pk[k];   // colsum
    }

    // cross-wave reduce through LDS (4 serialized rounds)
    __syncthreads();
    for (int round = 0; round < 4; ++round) {
        if (q == round) {
            #pragma unroll
            for (int k = 0; k < 8; ++k) {
                float* rp = &red2[(k*64 + lane)*25];
                if (round == 0) {
                    #pragma unroll
                    for (int r = 0; r < 25; ++r) rp[r] = acc[r][k];
                } else {
                    #pragma unroll
                    for (int r = 0; r < 25; ++r) rp[r] += acc[r][k];
                }
            }
        }
        __syncthreads();
    }

    // write ypart coalesced
    for (int l = tid; l < 25*VV; l += 256) {
        int w = l & (VV-1), r = l >> 9;
        ypart[((size_t)(s*NB + n)*25 + r)*VV + w] = red2[w*25 + r];
    }
}

// ---------------------------------------------------------------------------
// Kernel 3: out[n,o,t,w] = sum_c conv_w[o,c]*y[c*6+t,w] + conv_b[o]*y[24,w]
// Stages + split-reduces ypart through LDS exactly once.
// ---------------------------------------------------------------------------
__global__ __launch_bounds__(256) void expand_kernel(
    const float* __restrict__ ypart,
    const float* __restrict__ conv_w,
    const float* __restrict__ conv_b,
    float*       __restrict__ out)
{
    __shared__ float ysm[25][64];
    __shared__ float wsm[COUT*CIN];
    __shared__ float bsm[COUT];

    int wc = blockIdx.x;                 // 8 w-chunks of 64
    int n  = blockIdx.y;
    int tid = threadIdx.x;

    if (tid < COUT*CIN) wsm[tid] = conv_w[tid];
    if (tid < COUT)     bsm[tid] = conv_b[tid];

    // stage + reduce splits: 25*64 = 1600 floats as 400 float4
    for (int l4 = tid; l4 < 400; l4 += 256) {
        int r = l4 >> 4, w4 = l4 & 15;
        float4 a = {0.f, 0.f, 0.f, 0.f};
        #pragma unroll
        for (int s = 0; s < SPLITS; ++s) {
            float4 v = *(const float4*)(ypart +
                ((size_t)(s*NB + n)*25 + r)*VV + wc*64 + w4*4);
            a.x += v.x; a.y += v.y; a.z += v.z; a.w += v.w;
        }
        *(float4*)&ysm[r][w4*4] = a;
    }
    __syncthreads();

    int w  = tid & 63;
    int og = tid >> 6;                   // 4 groups x 16 o

    float y[25];
    #pragma unroll
    for (int r = 0; r < 25; ++r) y[r] = ysm[r][w];

    #pragma unroll
    for (int oo = 0; oo < 16; ++oo) {
        int o = og*16 + oo;
        float wb[CIN];
        #pragma unroll
        for (int c = 0; c < CIN; ++c) wb[c] = wsm[o*CIN + c];
        float bo = bsm[o];
        #pragma unroll
        for (int t = 0; t < TT; ++t) {
            float val = bo * y[24];
            #pragma unroll
            for (int c = 0; c < CIN; ++c) val = fmaf(wb[c], y[c*TT + t], val);
            out[((size_t)(n*COUT + o)*TT + t)*VV + wc*64 + w] = val;
        }
    }
}

// ---------------------------------------------------------------------------
extern "C" void kernel_launch(void* const* d_in, const int* in_sizes, int n_in,
                              void* d_out, int out_size, void* d_ws, size_t ws_size,
                              hipStream_t stream)
{
    const float* x      = (const float*)d_in[0];
    const int*   A      = (const int*)  d_in[1];
    const float* conv_w = (const float*)d_in[2];
    const float* conv_b = (const float*)d_in[3];
    const float* l2_w   = (const float*)d_in[4];
    const float* l2_b   = (const float*)d_in[5];
    const float* l1_w   = (const float*)d_in[6];
    const float* l1_b   = (const float*)d_in[7];

    float* out = (float*)d_out;
    float* pP  = out + P_OFF;              // p region of d_out
    float* e   = (float*)d_ws;             // 128 KB
    float* yp  = e + E_FLOATS;             // SPLITS*NB*25*VV f32 = 13.1 MB

    e_kernel<<<NB*VV/256, 256, 0, stream>>>(x, conv_w, conv_b, l2_w, l2_b, l1_w, e);

    dim3 gf(SPLITS, NB);                   // 256 blocks
    fused_kernel<<<gf, 256, 0, stream>>>(x, A, e, l1_b, pP, yp);

    dim3 ge(8, NB);                        // 256 blocks
    expand_kernel<<<ge, 256, 0, stream>>>(yp, conv_w, conv_b, out);
}

// Round 5
// 39.219 us; speedup vs baseline: 1.4321x; 1.4321x over previous
//
#include <hip/hip_runtime.h>
#include <math.h>

#define NB   32
#define CIN  4
#define COUT 64
#define TT   6
#define VV   512
#define P_OFF (NB*COUT*TT*VV)   // out then p in d_out
#define SPLITS 8
#define CH   (VV/SPLITS)        // 64 softmax rows per block
#define NROW 24                 // c*6+t rows of x per batch
#define E_FLOATS (2*NB*VV)      // e_i + e_j in ws

// ---------------------------------------------------------------------------
// Kernel 1: e_i[n,v], e_j[n,v]  (collapsed xc -> x1 -> e chain)
// ---------------------------------------------------------------------------
__global__ __launch_bounds__(256) void e_kernel(
    const float* __restrict__ x,
    const float* __restrict__ conv_w,
    const float* __restrict__ conv_b,
    const float* __restrict__ l2_w,
    const float* __restrict__ l2_b,
    const float* __restrict__ l1_w,
    float* __restrict__ e)
{
    __shared__ float W1[CIN], W2[CIN], cst[2];
    int tid = threadIdx.x;
    if (tid < CIN) {
        float w1 = 0.f, w2 = 0.f;
        for (int o = 0; o < COUT; ++o) {
            w1 += l1_w[o]        * conv_w[o*CIN + tid];
            w2 += l1_w[COUT + o] * conv_w[o*CIN + tid];
        }
        W1[tid] = w1; W2[tid] = w2;
    }
    if (tid == CIN) {
        float B1 = 0.f, B2 = 0.f, S1 = 0.f, S2 = 0.f;
        for (int o = 0; o < COUT; ++o) {
            B1 += l1_w[o]        * conv_b[o];
            B2 += l1_w[COUT + o] * conv_b[o];
            S1 += l1_w[o];
            S2 += l1_w[COUT + o];
        }
        float Ls = 0.f;
        for (int t = 0; t < TT; ++t) Ls += l2_w[t];
        cst[0] = Ls*B1 + l2_b[0]*S1;
        cst[1] = Ls*B2 + l2_b[0]*S2;
    }
    __syncthreads();

    int idx = blockIdx.x * 256 + tid;      // n*V + v
    int n = idx >> 9, v = idx & (VV-1);
    float ei = cst[0], ej = cst[1];
    #pragma unroll
    for (int c = 0; c < CIN; ++c) {
        float wc1 = W1[c], wc2 = W2[c];
        #pragma unroll
        for (int t = 0; t < TT; ++t) {
            float xv = x[((n*CIN + c)*TT + t)*VV + v];
            float lw = l2_w[t];
            ei += lw*wc1*xv;
            ej += lw*wc2*xv;
        }
    }
    e[idx]         = ei;
    e[NB*VV + idx] = ej;
}

// ---------------------------------------------------------------------------
// Kernel 2 (fused, spill-free): per block (s,n): 64 softmax rows -> p, and
// y_part[r][w] = sum_{i in chunk} x[n,r,i]*p[n,i,w].
// 8 waves: each computes 2 softmax rows per 16-row sub-chunk (j = lane*8+m),
// stages p rows in LDS, then accumulates its (r-group, w-half) slice:
// acc[6][4] per lane (rg = q>>1 owns rows rg*6..+5, wh = q&1 owns w-half).
// ---------------------------------------------------------------------------
__global__ __launch_bounds__(512, 2) void fused_kernel(
    const float* __restrict__ x,
    const int*   __restrict__ A,
    const float* __restrict__ e,
    const float* __restrict__ l1_b,
    float*       __restrict__ p,
    float*       __restrict__ ypart)
{
    __shared__ float xst[NROW][CH];      // [r][i_local] 6 KB
    __shared__ float ps[16][VV];         // 32 KB p-row stage

    int s = blockIdx.x;                  // 8 chunks of 64 rows
    int n = blockIdx.y;
    int tid = threadIdx.x;
    int lane = tid & 63;
    int q = tid >> 6;                    // wave 0..7
    int rg = q >> 1;                     // r-group 0..3 (6 rows each)
    int wh = q & 1;                      // w-half

    // stage x slab: xst[r][i], coalesced
    for (int l = tid; l < NROW*CH; l += 512) {
        int r = l >> 6, i = l & 63;
        xst[r][i] = x[((size_t)n*NROW + r)*VV + s*CH + i];
    }

    float l1b_val = l1_b[0];
    float4 ej0 = *(const float4*)(e + NB*VV + n*VV + lane*8);
    float4 ej1 = *(const float4*)(e + NB*VV + n*VV + lane*8 + 4);
    float ejv[8] = {ej0.x, ej0.y, ej0.z, ej0.w, ej1.x, ej1.y, ej1.z, ej1.w};

    const int* mbase = A + (size_t)(n*8 + 7)*VV*VV;

    float acc[6][4];
    #pragma unroll
    for (int rr = 0; rr < 6; ++rr)
        #pragma unroll
        for (int k = 0; k < 4; ++k) acc[rr][k] = 0.f;
    float a24[4] = {0.f, 0.f, 0.f, 0.f};

    // prefetch sub 0 rows for this wave
    int iA0 = s*CH + q*2;
    int4 mA0, mA1, mB0, mB1;
    float bA, bB;
    {
        const int* mrA = mbase + (size_t)iA0*VV + lane*8;
        mA0 = *(const int4*)mrA;       mA1 = *(const int4*)(mrA + 4);
        mB0 = *(const int4*)(mrA+VV);  mB1 = *(const int4*)(mrA + VV + 4);
        bA = e[n*VV + iA0]; bB = e[n*VV + iA0 + 1];
    }

    __syncthreads();   // xst ready

    for (int sub = 0; sub < 4; ++sub) {
        int ilA  = sub*16 + q*2;         // local row (wave's row A)
        int i_gA = s*CH + ilA;

        int4 cA0 = mA0, cA1 = mA1, cB0 = mB0, cB1 = mB1;
        float biasA = bA + l1b_val, biasB = bB + l1b_val;

        if (sub < 3) {                   // prefetch next sub's rows
            const int* mrA = mbase + (size_t)(i_gA + 16)*VV + lane*8;
            mA0 = *(const int4*)mrA;       mA1 = *(const int4*)(mrA + 4);
            mB0 = *(const int4*)(mrA+VV);  mB1 = *(const int4*)(mrA + VV + 4);
            bA = e[n*VV + i_gA + 16]; bB = e[n*VV + i_gA + 17];
        }

        // ---- softmax rows A & B (interleaved, j = lane*8 + m) ----
        float svA[8], svB[8];
        int mkA[8] = {cA0.x,cA0.y,cA0.z,cA0.w, cA1.x,cA1.y,cA1.z,cA1.w};
        int mkB[8] = {cB0.x,cB0.y,cB0.z,cB0.w, cB1.x,cB1.y,cB1.z,cB1.w};
        #pragma unroll
        for (int m2 = 0; m2 < 8; ++m2) {
            float tA = biasA + ejv[m2]; tA = (tA >= 0.f) ? tA : 0.2f*tA;
            svA[m2] = (mkA[m2] == 0) ? -INFINITY : tA;
            float tB = biasB + ejv[m2]; tB = (tB >= 0.f) ? tB : 0.2f*tB;
            svB[m2] = (mkB[m2] == 0) ? -INFINITY : tB;
        }
        float mA = svA[0], mB = svB[0];
        #pragma unroll
        for (int m2 = 1; m2 < 8; ++m2) {
            mA = fmaxf(mA, svA[m2]); mB = fmaxf(mB, svB[m2]);
        }
        #pragma unroll
        for (int off = 32; off; off >>= 1) {
            mA = fmaxf(mA, __shfl_xor(mA, off));
            mB = fmaxf(mB, __shfl_xor(mB, off));
        }
        float sumA = 0.f, sumB = 0.f;
        if (mA > -INFINITY) {
            #pragma unroll
            for (int m2 = 0; m2 < 8; ++m2) { svA[m2] = __expf(svA[m2]-mA); sumA += svA[m2]; }
        } else {
            #pragma unroll
            for (int m2 = 0; m2 < 8; ++m2) svA[m2] = 0.f;
        }
        if (mB > -INFINITY) {
            #pragma unroll
            for (int m2 = 0; m2 < 8; ++m2) { svB[m2] = __expf(svB[m2]-mB); sumB += svB[m2]; }
        } else {
            #pragma unroll
            for (int m2 = 0; m2 < 8; ++m2) svB[m2] = 0.f;
        }
        #pragma unroll
        for (int off = 32; off; off >>= 1) {
            sumA += __shfl_xor(sumA, off);
            sumB += __shfl_xor(sumB, off);
        }
        float invA = (sumA > 0.f) ? 1.f/sumA : 0.f;
        float invB = (sumB > 0.f) ? 1.f/sumB : 0.f;

        float4 pA03 = {svA[0]*invA, svA[1]*invA, svA[2]*invA, svA[3]*invA};
        float4 pA47 = {svA[4]*invA, svA[5]*invA, svA[6]*invA, svA[7]*invA};
        float4 pB03 = {svB[0]*invB, svB[1]*invB, svB[2]*invB, svB[3]*invB};
        float4 pB47 = {svB[4]*invB, svB[5]*invB, svB[6]*invB, svB[7]*invB};

        // global p stores (16B/lane, coalesced)
        float* prA = p + ((size_t)(n*VV + i_gA))*VV + lane*8;
        *(float4*)prA        = pA03;
        *(float4*)(prA + 4)  = pA47;
        *(float4*)(prA + VV)     = pB03;
        *(float4*)(prA + VV + 4) = pB47;

        // LDS p-row stage
        *(float4*)&ps[q*2][lane*8]       = pA03;
        *(float4*)&ps[q*2][lane*8 + 4]   = pA47;
        *(float4*)&ps[q*2+1][lane*8]     = pB03;
        *(float4*)&ps[q*2+1][lane*8 + 4] = pB47;

        __syncthreads();   // ps ready

        // ---- accumulate this wave's (rg, wh) slice over the 16 rows ----
        #pragma unroll
        for (int i = 0; i < 16; ++i) {
            float pv0 = ps[i][wh*256 + 0*64 + lane];
            float pv1 = ps[i][wh*256 + 1*64 + lane];
            float pv2 = ps[i][wh*256 + 2*64 + lane];
            float pv3 = ps[i][wh*256 + 3*64 + lane];
            #pragma unroll
            for (int rr = 0; rr < 6; ++rr) {
                float xv = xst[rg*6 + rr][sub*16 + i];
                acc[rr][0] = fmaf(xv, pv0, acc[rr][0]);
                acc[rr][1] = fmaf(xv, pv1, acc[rr][1]);
                acc[rr][2] = fmaf(xv, pv2, acc[rr][2]);
                acc[rr][3] = fmaf(xv, pv3, acc[rr][3]);
            }
            a24[0] += pv0; a24[1] += pv1; a24[2] += pv2; a24[3] += pv3;
        }
        __syncthreads();   // before next sub overwrites ps
    }

    // ---- write ypart (coalesced 256B stores) ----
    float* yo = ypart + (size_t)(s*NB + n)*25*VV + wh*256 + lane;
    #pragma unroll
    for (int rr = 0; rr < 6; ++rr)
        #pragma unroll
        for (int k = 0; k < 4; ++k)
            yo[(size_t)(rg*6 + rr)*VV + k*64] = acc[rr][k];
    if (rg == 0) {
        #pragma unroll
        for (int k = 0; k < 4; ++k)
            yo[(size_t)24*VV + k*64] = a24[k];
    }
}

// ---------------------------------------------------------------------------
// Kernel 3: out[n,o,t,w] = sum_c conv_w[o,c]*y[c*6+t,w] + conv_b[o]*y[24,w]
// Stages + split-reduces ypart through LDS exactly once.
// ---------------------------------------------------------------------------
__global__ __launch_bounds__(256) void expand_kernel(
    const float* __restrict__ ypart,
    const float* __restrict__ conv_w,
    const float* __restrict__ conv_b,
    float*       __restrict__ out)
{
    __shared__ float ysm[25][64];
    __shared__ float wsm[COUT*CIN];
    __shared__ float bsm[COUT];

    int wc = blockIdx.x;                 // 8 w-chunks of 64
    int n  = blockIdx.y;
    int tid = threadIdx.x;

    if (tid < COUT*CIN) wsm[tid] = conv_w[tid];
    if (tid < COUT)     bsm[tid] = conv_b[tid];

    // stage + reduce splits: 25*64 = 1600 floats as 400 float4
    for (int l4 = tid; l4 < 400; l4 += 256) {
        int r = l4 >> 4, w4 = l4 & 15;
        float4 a = {0.f, 0.f, 0.f, 0.f};
        #pragma unroll
        for (int s = 0; s < SPLITS; ++s) {
            float4 v = *(const float4*)(ypart +
                ((size_t)(s*NB + n)*25 + r)*VV + wc*64 + w4*4);
            a.x += v.x; a.y += v.y; a.z += v.z; a.w += v.w;
        }
        *(float4*)&ysm[r][w4*4] = a;
    }
    __syncthreads();

    int w  = tid & 63;
    int og = tid >> 6;                   // 4 groups x 16 o

    float y[25];
    #pragma unroll
    for (int r = 0; r < 25; ++r) y[r] = ysm[r][w];

    #pragma unroll
    for (int oo = 0; oo < 16; ++oo) {
        int o = og*16 + oo;
        float wb[CIN];
        #pragma unroll
        for (int c = 0; c < CIN; ++c) wb[c] = wsm[o*CIN + c];
        float bo = bsm[o];
        #pragma unroll
        for (int t = 0; t < TT; ++t) {
            float val = bo * y[24];
            #pragma unroll
            for (int c = 0; c < CIN; ++c) val = fmaf(wb[c], y[c*TT + t], val);
            out[((size_t)(n*COUT + o)*TT + t)*VV + wc*64 + w] = val;
        }
    }
}

// ---------------------------------------------------------------------------
extern "C" void kernel_launch(void* const* d_in, const int* in_sizes, int n_in,
                              void* d_out, int out_size, void* d_ws, size_t ws_size,
                              hipStream_t stream)
{
    const float* x      = (const float*)d_in[0];
    const int*   A      = (const int*)  d_in[1];
    const float* conv_w = (const float*)d_in[2];
    const float* conv_b = (const float*)d_in[3];
    const float* l2_w   = (const float*)d_in[4];
    const float* l2_b   = (const float*)d_in[5];
    const float* l1_w   = (const float*)d_in[6];
    const float* l1_b   = (const float*)d_in[7];

    float* out = (float*)d_out;
    float* pP  = out + P_OFF;              // p region of d_out
    float* e   = (float*)d_ws;             // 128 KB
    float* yp  = e + E_FLOATS;             // SPLITS*NB*25*VV f32 = 13.1 MB

    e_kernel<<<NB*VV/256, 256, 0, stream>>>(x, conv_w, conv_b, l2_w, l2_b, l1_w, e);

    dim3 gf(SPLITS, NB);                   // 256 blocks x 512 thr
    fused_kernel<<<gf, 512, 0, stream>>>(x, A, e, l1_b, pP, yp);

    dim3 ge(8, NB);                        // 256 blocks
    expand_kernel<<<ge, 256, 0, stream>>>(yp, conv_w, conv_b, out);
}

// Round 6
// 37.959 us; speedup vs baseline: 1.4796x; 1.0332x over previous
//
#include <hip/hip_runtime.h>
#include <math.h>

#define NB   32
#define CIN  4
#define COUT 64
#define TT   6
#define VV   512
#define P_OFF (NB*COUT*TT*VV)   // out then p in d_out
#define SPLITS 8
#define CH   (VV/SPLITS)        // 64 softmax rows per block
#define NROW 24                 // c*6+t rows of x per batch
#define E_FLOATS (2*NB*VV)      // e_i + e_j in ws

// ---------------------------------------------------------------------------
// Kernel 1: e_i[n,v], e_j[n,v]  (collapsed xc -> x1 -> e chain)
// ---------------------------------------------------------------------------
__global__ __launch_bounds__(256) void e_kernel(
    const float* __restrict__ x,
    const float* __restrict__ conv_w,
    const float* __restrict__ conv_b,
    const float* __restrict__ l2_w,
    const float* __restrict__ l2_b,
    const float* __restrict__ l1_w,
    float* __restrict__ e)
{
    __shared__ float W1[CIN], W2[CIN], cst[2];
    int tid = threadIdx.x;
    if (tid < CIN) {
        float w1 = 0.f, w2 = 0.f;
        for (int o = 0; o < COUT; ++o) {
            w1 += l1_w[o]        * conv_w[o*CIN + tid];
            w2 += l1_w[COUT + o] * conv_w[o*CIN + tid];
        }
        W1[tid] = w1; W2[tid] = w2;
    }
    if (tid == CIN) {
        float B1 = 0.f, B2 = 0.f, S1 = 0.f, S2 = 0.f;
        for (int o = 0; o < COUT; ++o) {
            B1 += l1_w[o]        * conv_b[o];
            B2 += l1_w[COUT + o] * conv_b[o];
            S1 += l1_w[o];
            S2 += l1_w[COUT + o];
        }
        float Ls = 0.f;
        for (int t = 0; t < TT; ++t) Ls += l2_w[t];
        cst[0] = Ls*B1 + l2_b[0]*S1;
        cst[1] = Ls*B2 + l2_b[0]*S2;
    }
    __syncthreads();

    int idx = blockIdx.x * 256 + tid;      // n*V + v
    int n = idx >> 9, v = idx & (VV-1);
    float ei = cst[0], ej = cst[1];
    #pragma unroll
    for (int c = 0; c < CIN; ++c) {
        float wc1 = W1[c], wc2 = W2[c];
        #pragma unroll
        for (int t = 0; t < TT; ++t) {
            float xv = x[((n*CIN + c)*TT + t)*VV + v];
            float lw = l2_w[t];
            ei += lw*wc1*xv;
            ej += lw*wc2*xv;
        }
    }
    e[idx]         = ei;
    e[NB*VV + idx] = ej;
}

// ---------------------------------------------------------------------------
// Kernel 2 (fused): per block (s,n): 64 softmax rows -> p (global) and
// y_part[r][w] = sum_{i in chunk} x[n,r,i]*p[n,i,w].
// 8 waves: wave q computes 2 softmax rows per 16-row sub (j = lane*8+m),
// stages them in double-buffered LDS (1 barrier/sub), then accumulates its
// (r-group rg = q>>1, w-quarter-pair wh = q&1) slice: acc[6][4] per lane,
// w = wh*256 + lane*4 + k  (b128 p-reads, b128 ypart stores).
// ---------------------------------------------------------------------------
__global__ __launch_bounds__(512, 2) void fused_kernel(
    const float* __restrict__ x,
    const int*   __restrict__ A,
    const float* __restrict__ e,
    const float* __restrict__ l1_b,
    float*       __restrict__ p,
    float*       __restrict__ ypart)
{
    __shared__ float xst[CH][4][8];      // [i][rg][rr] 8 KB (slots 6,7 pad)
    __shared__ float ps[2][16][VV];      // 64 KB double-buffered p stage

    int s = blockIdx.x;                  // 8 chunks of 64 rows
    int n = blockIdx.y;
    int tid = threadIdx.x;
    int lane = tid & 63;
    int q = tid >> 6;                    // wave 0..7
    int rg = q >> 1;                     // r-group 0..3 (6 rows each)
    int wh = q & 1;                      // w-half

    // stage x slab: xst[i][r/6][r%6]
    for (int l = tid; l < NROW*CH; l += 512) {
        int r = l >> 6, i = l & 63;
        xst[i][r/6][r%6] = x[((size_t)n*NROW + r)*VV + s*CH + i];
    }

    float l1b_val = l1_b[0];
    float4 ej0 = *(const float4*)(e + NB*VV + n*VV + lane*8);
    float4 ej1 = *(const float4*)(e + NB*VV + n*VV + lane*8 + 4);
    float ejv[8] = {ej0.x, ej0.y, ej0.z, ej0.w, ej1.x, ej1.y, ej1.z, ej1.w};

    const int* mbase = A + (size_t)(n*8 + 7)*VV*VV;

    float acc[6][4];
    #pragma unroll
    for (int rr = 0; rr < 6; ++rr)
        #pragma unroll
        for (int k = 0; k < 4; ++k) acc[rr][k] = 0.f;
    float a24[4] = {0.f, 0.f, 0.f, 0.f};

    // prefetch sub 0 rows for this wave (rows q*2, q*2+1)
    int iA0 = s*CH + q*2;
    int4 mA0, mA1, mB0, mB1;
    float bA, bB;
    {
        const int* mrA = mbase + (size_t)iA0*VV + lane*8;
        mA0 = *(const int4*)mrA;       mA1 = *(const int4*)(mrA + 4);
        mB0 = *(const int4*)(mrA+VV);  mB1 = *(const int4*)(mrA + VV + 4);
        bA = e[n*VV + iA0]; bB = e[n*VV + iA0 + 1];
    }
    // NOTE: no barrier needed here — xst first read is after sub0's barrier.

    for (int sub = 0; sub < 4; ++sub) {
        int i_gA = s*CH + sub*16 + q*2;

        int4 cA0 = mA0, cA1 = mA1, cB0 = mB0, cB1 = mB1;
        float biasA = bA + l1b_val, biasB = bB + l1b_val;

        if (sub < 3) {                   // prefetch next sub's rows
            const int* mrA = mbase + (size_t)(i_gA + 16)*VV + lane*8;
            mA0 = *(const int4*)mrA;       mA1 = *(const int4*)(mrA + 4);
            mB0 = *(const int4*)(mrA+VV);  mB1 = *(const int4*)(mrA + VV + 4);
            bA = e[n*VV + i_gA + 16]; bB = e[n*VV + i_gA + 17];
        }

        // ---- softmax rows A & B (j = lane*8 + m) ----
        float svA[8], svB[8];
        int mkA[8] = {cA0.x,cA0.y,cA0.z,cA0.w, cA1.x,cA1.y,cA1.z,cA1.w};
        int mkB[8] = {cB0.x,cB0.y,cB0.z,cB0.w, cB1.x,cB1.y,cB1.z,cB1.w};
        #pragma unroll
        for (int m2 = 0; m2 < 8; ++m2) {
            float tA = biasA + ejv[m2]; tA = (tA >= 0.f) ? tA : 0.2f*tA;
            svA[m2] = (mkA[m2] == 0) ? -INFINITY : tA;
            float tB = biasB + ejv[m2]; tB = (tB >= 0.f) ? tB : 0.2f*tB;
            svB[m2] = (mkB[m2] == 0) ? -INFINITY : tB;
        }
        float mA = svA[0], mB = svB[0];
        #pragma unroll
        for (int m2 = 1; m2 < 8; ++m2) {
            mA = fmaxf(mA, svA[m2]); mB = fmaxf(mB, svB[m2]);
        }
        #pragma unroll
        for (int off = 32; off; off >>= 1) {
            mA = fmaxf(mA, __shfl_xor(mA, off));
            mB = fmaxf(mB, __shfl_xor(mB, off));
        }
        float sumA = 0.f, sumB = 0.f;
        if (mA > -INFINITY) {
            #pragma unroll
            for (int m2 = 0; m2 < 8; ++m2) { svA[m2] = __expf(svA[m2]-mA); sumA += svA[m2]; }
        } else {
            #pragma unroll
            for (int m2 = 0; m2 < 8; ++m2) svA[m2] = 0.f;
        }
        if (mB > -INFINITY) {
            #pragma unroll
            for (int m2 = 0; m2 < 8; ++m2) { svB[m2] = __expf(svB[m2]-mB); sumB += svB[m2]; }
        } else {
            #pragma unroll
            for (int m2 = 0; m2 < 8; ++m2) svB[m2] = 0.f;
        }
        #pragma unroll
        for (int off = 32; off; off >>= 1) {
            sumA += __shfl_xor(sumA, off);
            sumB += __shfl_xor(sumB, off);
        }
        float invA = (sumA > 0.f) ? 1.f/sumA : 0.f;
        float invB = (sumB > 0.f) ? 1.f/sumB : 0.f;

        float4 pA03 = {svA[0]*invA, svA[1]*invA, svA[2]*invA, svA[3]*invA};
        float4 pA47 = {svA[4]*invA, svA[5]*invA, svA[6]*invA, svA[7]*invA};
        float4 pB03 = {svB[0]*invB, svB[1]*invB, svB[2]*invB, svB[3]*invB};
        float4 pB47 = {svB[4]*invB, svB[5]*invB, svB[6]*invB, svB[7]*invB};

        // global p stores (16B/lane, coalesced)
        float* prA = p + ((size_t)(n*VV + i_gA))*VV + lane*8;
        *(float4*)prA            = pA03;
        *(float4*)(prA + 4)      = pA47;
        *(float4*)(prA + VV)     = pB03;
        *(float4*)(prA + VV + 4) = pB47;

        // LDS p-row stage (buffer sub&1)
        float* pd = &ps[sub & 1][q*2][lane*8];
        *(float4*)pd          = pA03;
        *(float4*)(pd + 4)    = pA47;
        *(float4*)(pd + VV)   = pB03;
        *(float4*)(pd + VV+4) = pB47;

        __syncthreads();   // ps[sub&1] ready (single barrier per sub)

        // ---- accumulate (rg, wh) slice: w = wh*256 + lane*4 + k ----
        const float (*psb)[VV] = ps[sub & 1];
        #pragma unroll
        for (int i = 0; i < 16; ++i) {
            float4 pv = *(const float4*)&psb[i][wh*256 + lane*4];
            float4 xa = *(const float4*)&xst[sub*16 + i][rg][0];
            float2 xb = *(const float2*)&xst[sub*16 + i][rg][4];
            float xr[6] = {xa.x, xa.y, xa.z, xa.w, xb.x, xb.y};
            float pvk[4] = {pv.x, pv.y, pv.z, pv.w};
            #pragma unroll
            for (int rr = 0; rr < 6; ++rr)
                #pragma unroll
                for (int k = 0; k < 4; ++k)
                    acc[rr][k] = fmaf(xr[rr], pvk[k], acc[rr][k]);
            if (rg == 0) {
                #pragma unroll
                for (int k = 0; k < 4; ++k) a24[k] += pvk[k];
            }
        }
        // next sub writes the other buffer; this sub's barrier fences reuse
    }

    // ---- write ypart (b128, coalesced) ----
    float* yo = ypart + (size_t)(s*NB + n)*25*VV + wh*256 + lane*4;
    #pragma unroll
    for (int rr = 0; rr < 6; ++rr) {
        float4 st = {acc[rr][0], acc[rr][1], acc[rr][2], acc[rr][3]};
        *(float4*)(yo + (size_t)(rg*6 + rr)*VV) = st;
    }
    if (rg == 0) {
        float4 st = {a24[0], a24[1], a24[2], a24[3]};
        *(float4*)(yo + (size_t)24*VV) = st;
    }
}

// ---------------------------------------------------------------------------
// Kernel 3: out[n,o,t,w] = sum_c conv_w[o,c]*y[c*6+t,w] + conv_b[o]*y[24,w]
// Stages + split-reduces ypart through LDS exactly once.
// ---------------------------------------------------------------------------
__global__ __launch_bounds__(256) void expand_kernel(
    const float* __restrict__ ypart,
    const float* __restrict__ conv_w,
    const float* __restrict__ conv_b,
    float*       __restrict__ out)
{
    __shared__ float ysm[25][64];
    __shared__ float wsm[COUT*CIN];
    __shared__ float bsm[COUT];

    int wc = blockIdx.x;                 // 8 w-chunks of 64
    int n  = blockIdx.y;
    int tid = threadIdx.x;

    if (tid < COUT*CIN) wsm[tid] = conv_w[tid];
    if (tid < COUT)     bsm[tid] = conv_b[tid];

    // stage + reduce splits: 25*64 = 1600 floats as 400 float4
    for (int l4 = tid; l4 < 400; l4 += 256) {
        int r = l4 >> 4, w4 = l4 & 15;
        float4 a = {0.f, 0.f, 0.f, 0.f};
        #pragma unroll
        for (int s = 0; s < SPLITS; ++s) {
            float4 v = *(const float4*)(ypart +
                ((size_t)(s*NB + n)*25 + r)*VV + wc*64 + w4*4);
            a.x += v.x; a.y += v.y; a.z += v.z; a.w += v.w;
        }
        *(float4*)&ysm[r][w4*4] = a;
    }
    __syncthreads();

    int w  = tid & 63;
    int og = tid >> 6;                   // 4 groups x 16 o

    float y[25];
    #pragma unroll
    for (int r = 0; r < 25; ++r) y[r] = ysm[r][w];

    #pragma unroll
    for (int oo = 0; oo < 16; ++oo) {
        int o = og*16 + oo;
        float wb[CIN];
        #pragma unroll
        for (int c = 0; c < CIN; ++c) wb[c] = wsm[o*CIN + c];
        float bo = bsm[o];
        #pragma unroll
        for (int t = 0; t < TT; ++t) {
            float val = bo * y[24];
            #pragma unroll
            for (int c = 0; c < CIN; ++c) val = fmaf(wb[c], y[c*TT + t], val);
            out[((size_t)(n*COUT + o)*TT + t)*VV + wc*64 + w] = val;
        }
    }
}

// ---------------------------------------------------------------------------
extern "C" void kernel_launch(void* const* d_in, const int* in_sizes, int n_in,
                              void* d_out, int out_size, void* d_ws, size_t ws_size,
                              hipStream_t stream)
{
    const float* x      = (const float*)d_in[0];
    const int*   A      = (const int*)  d_in[1];
    const float* conv_w = (const float*)d_in[2];
    const float* conv_b = (const float*)d_in[3];
    const float* l2_w   = (const float*)d_in[4];
    const float* l2_b   = (const float*)d_in[5];
    const float* l1_w   = (const float*)d_in[6];
    const float* l1_b   = (const float*)d_in[7];

    float* out = (float*)d_out;
    float* pP  = out + P_OFF;              // p region of d_out
    float* e   = (float*)d_ws;             // 128 KB
    float* yp  = e + E_FLOATS;             // SPLITS*NB*25*VV f32 = 13.1 MB

    e_kernel<<<NB*VV/256, 256, 0, stream>>>(x, conv_w, conv_b, l2_w, l2_b, l1_w, e);

    dim3 gf(SPLITS, NB);                   // 256 blocks x 512 thr
    fused_kernel<<<gf, 512, 0, stream>>>(x, A, e, l1_b, pP, yp);

    dim3 ge(8, NB);                        // 256 blocks
    expand_kernel<<<ge, 256, 0, stream>>>(yp, conv_w, conv_b, out);
}